// Round 1
// baseline (1203.554 us; speedup 1.0000x reference)
//
#include <hip/hip_runtime.h>
#include <math.h>

// Problem constants (fixed by setup_inputs)
#define BATCH   2
#define LQ      21760
#define CDIM    256
#define NHEADS  8
#define NLEV    4
#define NPTS    4
#define HDIM    32
#define NPROJ   384          // 256 offset cols + 128 attn cols
#define QT      16           // queries per block; 43520/16 = 2720 blocks, no batch straddle

__global__ __launch_bounds__(256) void msda_fused(
    const float* __restrict__ query,     // [B][LQ][256]
    const float* __restrict__ refp,      // [B][LQ][2]
    const float* __restrict__ feat,      // [B][LQ][256]
    const float* __restrict__ Woff,      // [256][256]
    const float* __restrict__ boff,      // [256]
    const float* __restrict__ Wattn,     // [256][128]
    const float* __restrict__ battn,     // [128]
    const float* __restrict__ Wout,      // [256][256]
    const float* __restrict__ bout,      // [256]
    float* __restrict__ out)             // [B][LQ][256]
{
    __shared__ __align__(16) float xq[QT][CDIM];    // query rows; reused as `mid` after sampling
    __shared__ __align__(16) float proj[QT][NPROJ]; // per-query [off(256) | attn(128)]
    __shared__ float rp[QT][2];

    const int t  = threadIdx.x;
    const int q0 = blockIdx.x * QT;          // global row = b*LQ + q
    const int b  = q0 / LQ;                  // QT divides LQ -> uniform per block

    // ---- Phase A: stage 16 query rows (contiguous 16 KB) + ref points ----
    {
        const float4* src = (const float4*)(query + (size_t)q0 * CDIM);
        float4* dst = (float4*)&xq[0][0];
        #pragma unroll
        for (int i = 0; i < (QT * CDIM / 4) / 256; ++i)
            dst[t + i * 256] = src[t + i * 256];
        if (t < QT * 2)
            ((float*)rp)[t] = refp[(size_t)q0 * 2 + t];
    }
    __syncthreads();

    // ---- Phase B: projection GEMM: proj[q][c] = xq[q][:] . Wcol(c) + bias ----
    for (int c = t; c < NPROJ; c += 256) {
        const float* Wp; int ld; float bias;
        if (c < CDIM) { Wp = Woff  + c;          ld = 256; bias = boff[c]; }
        else          { Wp = Wattn + (c - CDIM); ld = 128; bias = battn[c - CDIM]; }
        float acc[QT];
        #pragma unroll
        for (int q = 0; q < QT; ++q) acc[q] = bias;
        for (int k = 0; k < CDIM; k += 4) {
            const float w0 = Wp[(size_t)(k + 0) * ld];
            const float w1 = Wp[(size_t)(k + 1) * ld];
            const float w2 = Wp[(size_t)(k + 2) * ld];
            const float w3 = Wp[(size_t)(k + 3) * ld];
            #pragma unroll
            for (int q = 0; q < QT; ++q) {
                float4 x4 = *(const float4*)&xq[q][k];
                acc[q] = fmaf(x4.x, w0, acc[q]);
                acc[q] = fmaf(x4.y, w1, acc[q]);
                acc[q] = fmaf(x4.z, w2, acc[q]);
                acc[q] = fmaf(x4.w, w3, acc[q]);
            }
        }
        #pragma unroll
        for (int q = 0; q < QT; ++q) proj[q][c] = acc[q];
    }
    __syncthreads();

    // ---- Phase C: softmax over the 16 attn logits per (q, h) ----
    if (t < QT * NHEADS) {                  // 128 active threads
        const int q = t >> 3, h = t & 7;
        float* a = &proj[q][CDIM + h * 16];
        float m = a[0];
        #pragma unroll
        for (int j = 1; j < 16; ++j) m = fmaxf(m, a[j]);
        float e[16], s = 0.f;
        #pragma unroll
        for (int j = 0; j < 16; ++j) { e[j] = __expf(a[j] - m); s += e[j]; }
        const float inv = 1.f / s;
        #pragma unroll
        for (int j = 0; j < 16; ++j) a[j] = e[j] * inv;
    }
    __syncthreads();

    // ---- Phase D: bilinear sampling; thread t -> (h = t>>5, d = t&31) ----
    {
        const int h = t >> 5, d = t & 31;
        const int LW[4] = {128, 64, 32, 16};
        const int LH[4] = {128, 64, 32, 16};
        const int LS[4] = {0, 16384, 20480, 21504};
        const float* featb = feat + (size_t)b * LQ * CDIM + h * HDIM + d;

        float midv[QT];
        #pragma unroll
        for (int q = 0; q < QT; ++q) {
            const float rx = rp[q][0], ry = rp[q][1];
            float accum = 0.f;
            #pragma unroll
            for (int l = 0; l < NLEV; ++l) {
                const int Wl = LW[l], Hl = LH[l], base = LS[l];
                #pragma unroll
                for (int p = 0; p < NPTS; ++p) {
                    const int oidx = ((h * NLEV + l) * NPTS + p) * 2;
                    const float ox = proj[q][oidx + 0];
                    const float oy = proj[q][oidx + 1];
                    const float aw = proj[q][CDIM + h * 16 + l * 4 + p];
                    const float x = rx * (float)Wl + ox - 0.5f;
                    const float y = ry * (float)Hl + oy - 0.5f;
                    const float x0f = floorf(x), y0f = floorf(y);
                    const float fx = x - x0f, fy = y - y0f;
                    const int ix = (int)x0f, iy = (int)y0f;

                    float v[4];
                    #pragma unroll
                    for (int c = 0; c < 4; ++c) {
                        const int cx = ix + (c & 1);
                        const int cy = iy + (c >> 1);
                        const bool ok = (cx >= 0) & (cx < Wl) & (cy >= 0) & (cy < Hl);
                        const int cxc = min(max(cx, 0), Wl - 1);
                        const int cyc = min(max(cy, 0), Hl - 1);
                        const float vv = featb[(size_t)(base + cyc * Wl + cxc) * CDIM];
                        v[c] = ok ? vv : 0.f;
                    }
                    const float w00 = (1.f - fx) * (1.f - fy);
                    const float w01 = fx * (1.f - fy);
                    const float w10 = (1.f - fx) * fy;
                    const float w11 = fx * fy;
                    accum = fmaf(aw, fmaf(w00, v[0], fmaf(w01, v[1], fmaf(w10, v[2], w11 * v[3]))), accum);
                }
            }
            midv[q] = accum;
        }
        __syncthreads();                     // done reading xq as query
        #pragma unroll
        for (int q = 0; q < QT; ++q) xq[q][t] = midv[q];   // xq now holds `mid`
    }
    __syncthreads();

    // ---- Phase E: output GEMM: out[q][n] = mid[q][:] . Wout[:,n] + bout[n] ----
    {
        const int n = t;
        float acc[QT];
        const float bo = bout[n];
        #pragma unroll
        for (int q = 0; q < QT; ++q) acc[q] = bo;
        for (int k = 0; k < CDIM; k += 4) {
            const float w0 = Wout[(size_t)(k + 0) * CDIM + n];
            const float w1 = Wout[(size_t)(k + 1) * CDIM + n];
            const float w2 = Wout[(size_t)(k + 2) * CDIM + n];
            const float w3 = Wout[(size_t)(k + 3) * CDIM + n];
            #pragma unroll
            for (int q = 0; q < QT; ++q) {
                float4 x4 = *(const float4*)&xq[q][k];
                acc[q] = fmaf(x4.x, w0, acc[q]);
                acc[q] = fmaf(x4.y, w1, acc[q]);
                acc[q] = fmaf(x4.z, w2, acc[q]);
                acc[q] = fmaf(x4.w, w3, acc[q]);
            }
        }
        #pragma unroll
        for (int q = 0; q < QT; ++q)
            out[(size_t)(q0 + q) * CDIM + n] = acc[q];
    }
}

extern "C" void kernel_launch(void* const* d_in, const int* in_sizes, int n_in,
                              void* d_out, int out_size, void* d_ws, size_t ws_size,
                              hipStream_t stream) {
    const float* query = (const float*)d_in[0];
    const float* refp  = (const float*)d_in[1];
    const float* feat  = (const float*)d_in[2];
    // d_in[3] spatial_shapes, d_in[4] level_start_index: fixed, hardcoded
    const float* Woff  = (const float*)d_in[5];
    const float* boff  = (const float*)d_in[6];
    const float* Wattn = (const float*)d_in[7];
    const float* battn = (const float*)d_in[8];
    const float* Wout  = (const float*)d_in[9];
    const float* bout  = (const float*)d_in[10];
    float* out = (float*)d_out;

    const int nrows = BATCH * LQ;            // 43520
    dim3 grid(nrows / QT), block(256);
    hipLaunchKernelGGL(msda_fused, grid, block, 0, stream,
                       query, refp, feat, Woff, boff, Wattn, battn, Wout, bout, out);
}

// Round 2
// 526.639 us; speedup vs baseline: 2.2853x; 2.2853x over previous
//
#include <hip/hip_runtime.h>
#include <math.h>

// Problem constants (fixed by setup_inputs)
#define BATCH   2
#define LQ      21760
#define CDIM    256
#define NHEADS  8
#define NLEV    4
#define NPTS    4
#define HDIM    32
#define NPROJ   384          // 256 offset cols + 128 attn cols
#define QT      16           // queries per block; 43520/16 = 2720 blocks
#define PROJ_LD 388          // padded stride for proj LDS

typedef short  bf16x8 __attribute__((ext_vector_type(8)));
typedef float  f32x4  __attribute__((ext_vector_type(4)));

static __device__ __host__ inline unsigned short f2bf(float x) {
    unsigned int u = __builtin_bit_cast(unsigned int, x);
    unsigned int r = (u + 0x7fff + ((u >> 16) & 1)) >> 16;   // RNE
    return (unsigned short)r;
}

// ---- pack W into bf16 B-fragment-major layout in ws ----
// Entry id -> (tile tn, kstep s, lane l). 16B per entry:
//   B[k = s*32 + (l>>4)*8 + i][col = tn*16 + (l&15)], i=0..7
// Phase-B W = [Woff | Wattn]: 24 tiles * 8 steps * 64 lanes = 12288 entries.
// Phase-E W = Wout: 16 * 8 * 64 = 8192 entries.
__global__ __launch_bounds__(256) void pack_w(
    const float* __restrict__ Woff, const float* __restrict__ Wattn,
    const float* __restrict__ Wout, unsigned short* __restrict__ ws)
{
    const int id = blockIdx.x * 256 + threadIdx.x;   // 0 .. 20479
    bf16x8 pk;
    if (id < 12288) {
        const int lane = id & 63, s = (id >> 6) & 7, tn = id >> 9;
        const int col = tn * 16 + (lane & 15);
        const int k0  = s * 32 + (lane >> 4) * 8;
        #pragma unroll
        for (int i = 0; i < 8; ++i) {
            const int k = k0 + i;
            const float w = (col < 256) ? Woff[(size_t)k * 256 + col]
                                        : Wattn[(size_t)k * 128 + (col - 256)];
            pk[i] = (short)f2bf(w);
        }
        *(bf16x8*)(ws + (size_t)id * 8) = pk;
    } else {
        const int id2 = id - 12288;
        const int lane = id2 & 63, s = (id2 >> 6) & 7, tn = id2 >> 9;
        const int col = tn * 16 + (lane & 15);
        const int k0  = s * 32 + (lane >> 4) * 8;
        #pragma unroll
        for (int i = 0; i < 8; ++i)
            pk[i] = (short)f2bf(Wout[(size_t)(k0 + i) * 256 + col]);
        *(bf16x8*)(ws + (size_t)(12288 + id2) * 8) = pk;
    }
}

// A-frag reader: xqb is [16 rows][512 B] bf16, column-XOR-swizzled:
// element (row,k) lives at byte row*512 + ((k*2) ^ ((row&7)<<4))
static __device__ inline void load_afrags(const unsigned char* xqb, int lane, bf16x8* af) {
    const int row = lane & 15;
    const int kg8 = (lane >> 4) * 8;
    const int sw  = (row & 7) << 4;
    const int base = row * 512;
    #pragma unroll
    for (int s = 0; s < 8; ++s) {
        const int byte = base + (((s * 32 + kg8) * 2) ^ sw);
        af[s] = *(const bf16x8*)(xqb + byte);
    }
}

__global__ __launch_bounds__(256, 4) void msda_fused(
    const float* __restrict__ query,     // [B][LQ][256]
    const float* __restrict__ refp,      // [B][LQ][2]
    const float* __restrict__ feat,      // [B][LQ][256]
    const float* __restrict__ boff,      // [256]
    const float* __restrict__ battn,     // [128]
    const float* __restrict__ bout,      // [256]
    const unsigned short* __restrict__ wsB,   // packed [Woff|Wattn] frags
    const unsigned short* __restrict__ wsO,   // packed Wout frags
    float* __restrict__ out)             // [B][LQ][256]
{
    __shared__ __align__(16) unsigned char xqb[QT * 512];       // bf16 A-tile (query, then mid)
    __shared__ __align__(16) float proj[QT * PROJ_LD];          // [off(256)|attn(128)] per q
    __shared__ float rp[QT][2];

    const int t    = threadIdx.x;
    const int lane = t & 63;
    const int wid  = t >> 6;
    const int q0   = blockIdx.x * QT;
    const int b    = q0 / LQ;

    #define PROJ(q, c) proj[(q) * PROJ_LD + (c)]

    // ---- Phase A: stage 16 query rows as swizzled bf16 + ref points ----
    {
        const float4* src = (const float4*)(query + (size_t)q0 * CDIM);
        #pragma unroll
        for (int i = 0; i < 4; ++i) {
            const int idx = t + i * 256;          // 0..1023 float4s
            const int row = idx >> 6;             // 64 float4 per row
            const int k4  = (idx & 63) * 4;       // element k base
            const float4 v = src[idx];
            uint2 w;
            w.x = (unsigned int)f2bf(v.x) | ((unsigned int)f2bf(v.y) << 16);
            w.y = (unsigned int)f2bf(v.z) | ((unsigned int)f2bf(v.w) << 16);
            const int byte = row * 512 + (((k4 * 2)) ^ ((row & 7) << 4));
            *(uint2*)(xqb + byte) = w;
        }
        if (t < QT * 2) ((float*)rp)[t] = refp[(size_t)q0 * 2 + t];
    }
    __syncthreads();

    // ---- Phase B: proj[q][c] = query . [Woff|Wattn] + bias via MFMA ----
    {
        bf16x8 af[8];
        load_afrags(xqb, lane, af);
        const int colb = lane & 15;
        const int r0   = (lane >> 4) * 4;
        #pragma unroll
        for (int j = 0; j < 6; ++j) {
            const int tn  = wid * 6 + j;          // 0..23
            const int col = tn * 16 + colb;
            const float bv = (col < 256) ? boff[col] : battn[col - 256];
            f32x4 acc = {bv, bv, bv, bv};
            const bf16x8* bp = (const bf16x8*)wsB + (size_t)tn * 8 * 64 + lane;
            #pragma unroll
            for (int s = 0; s < 8; ++s)
                acc = __builtin_amdgcn_mfma_f32_16x16x32_bf16(af[s], bp[(size_t)s * 64], acc, 0, 0, 0);
            #pragma unroll
            for (int r = 0; r < 4; ++r) PROJ(r0 + r, col) = acc[r];
        }
    }
    __syncthreads();

    // ---- Phase C: softmax over the 16 attn logits per (q, h) ----
    if (t < QT * NHEADS) {
        const int q = t >> 3, h = t & 7;
        float* a = &PROJ(q, CDIM + h * 16);
        float m = a[0];
        #pragma unroll
        for (int j = 1; j < 16; ++j) m = fmaxf(m, a[j]);
        float e[16], s = 0.f;
        #pragma unroll
        for (int j = 0; j < 16; ++j) { e[j] = __expf(a[j] - m); s += e[j]; }
        const float inv = 1.f / s;
        #pragma unroll
        for (int j = 0; j < 16; ++j) a[j] = e[j] * inv;
    }
    __syncthreads();

    // ---- Phase D: bilinear sampling; thread t -> (h = t>>5, d = t&31) ----
    {
        const int h = t >> 5, d = t & 31;
        const int LW[4] = {128, 64, 32, 16};
        const int LS[4] = {0, 16384, 20480, 21504};
        const float* featb = feat + (size_t)b * LQ * CDIM + h * HDIM + d;

        float midv[QT];
        #pragma unroll
        for (int q = 0; q < QT; ++q) {
            const float rx = rp[q][0], ry = rp[q][1];
            float accum = 0.f;
            #pragma unroll
            for (int l = 0; l < NLEV; ++l) {
                const int Wl = LW[l], Hl = LW[l], base = LS[l];
                #pragma unroll
                for (int p = 0; p < NPTS; ++p) {
                    const int oidx = ((h * NLEV + l) * NPTS + p) * 2;
                    const float ox = PROJ(q, oidx + 0);
                    const float oy = PROJ(q, oidx + 1);
                    const float aw = PROJ(q, CDIM + h * 16 + l * 4 + p);
                    const float x = rx * (float)Wl + ox - 0.5f;
                    const float y = ry * (float)Hl + oy - 0.5f;
                    const float x0f = floorf(x), y0f = floorf(y);
                    const float fx = x - x0f, fy = y - y0f;
                    const int ix = (int)x0f, iy = (int)y0f;
                    float v[4];
                    #pragma unroll
                    for (int c = 0; c < 4; ++c) {
                        const int cx = ix + (c & 1);
                        const int cy = iy + (c >> 1);
                        const bool ok = (cx >= 0) & (cx < Wl) & (cy >= 0) & (cy < Hl);
                        const int cxc = min(max(cx, 0), Wl - 1);
                        const int cyc = min(max(cy, 0), Hl - 1);
                        const float vv = featb[(size_t)(base + cyc * Wl + cxc) * CDIM];
                        v[c] = ok ? vv : 0.f;
                    }
                    const float w00 = (1.f - fx) * (1.f - fy);
                    const float w01 = fx * (1.f - fy);
                    const float w10 = (1.f - fx) * fy;
                    const float w11 = fx * fy;
                    accum = fmaf(aw, fmaf(w00, v[0], fmaf(w01, v[1], fmaf(w10, v[2], w11 * v[3]))), accum);
                }
            }
            midv[q] = accum;
        }
        // write mid as swizzled bf16 into xqb (query is dead; all waves past Phase B)
        #pragma unroll
        for (int q = 0; q < QT; ++q) {
            const unsigned short hv = f2bf(midv[q]);
            *(unsigned short*)(xqb + q * 512 + (((t * 2)) ^ ((q & 7) << 4))) = hv;
        }
    }
    __syncthreads();

    // ---- Phase E: out[q][n] = mid . Wout + bout via MFMA, direct global store ----
    {
        bf16x8 af[8];
        load_afrags(xqb, lane, af);
        const int colb = lane & 15;
        const int r0   = (lane >> 4) * 4;
        #pragma unroll
        for (int j = 0; j < 4; ++j) {
            const int tn  = wid * 4 + j;          // 0..15
            const int col = tn * 16 + colb;
            const float bv = bout[col];
            f32x4 acc = {bv, bv, bv, bv};
            const bf16x8* bp = (const bf16x8*)wsO + (size_t)tn * 8 * 64 + lane;
            #pragma unroll
            for (int s = 0; s < 8; ++s)
                acc = __builtin_amdgcn_mfma_f32_16x16x32_bf16(af[s], bp[(size_t)s * 64], acc, 0, 0, 0);
            #pragma unroll
            for (int r = 0; r < 4; ++r)
                out[(size_t)(q0 + r0 + r) * CDIM + col] = acc[r];
        }
    }
    #undef PROJ
}

extern "C" void kernel_launch(void* const* d_in, const int* in_sizes, int n_in,
                              void* d_out, int out_size, void* d_ws, size_t ws_size,
                              hipStream_t stream) {
    const float* query = (const float*)d_in[0];
    const float* refp  = (const float*)d_in[1];
    const float* feat  = (const float*)d_in[2];
    const float* Woff  = (const float*)d_in[5];
    const float* boff  = (const float*)d_in[6];
    const float* Wattn = (const float*)d_in[7];
    const float* battn = (const float*)d_in[8];
    const float* Wout  = (const float*)d_in[9];
    const float* bout  = (const float*)d_in[10];
    float* out = (float*)d_out;

    unsigned short* ws = (unsigned short*)d_ws;
    const unsigned short* wsB = ws;                       // 12288 frags * 16B
    const unsigned short* wsO = ws + (size_t)12288 * 8;   // 8192 frags * 16B

    hipLaunchKernelGGL(pack_w, dim3(80), dim3(256), 0, stream, Woff, Wattn, Wout, ws);

    const int nrows = BATCH * LQ;            // 43520
    hipLaunchKernelGGL(msda_fused, dim3(nrows / QT), dim3(256), 0, stream,
                       query, refp, feat, boff, battn, bout, wsB, wsO, out);
}

// Round 3
// 159.072 us; speedup vs baseline: 7.5661x; 3.3107x over previous
//
#include <hip/hip_runtime.h>
#include <hip/hip_fp16.h>
#include <math.h>

// Problem constants (fixed by setup_inputs)
#define BATCH   2
#define LQ      21760
#define CDIM    256
#define NHEADS  8
#define NLEV    4
#define NPTS    4
#define HDIM    32
#define NPROJ   384          // 256 offset cols + 128 attn cols
#define QT      16           // queries per block; 43520/16 = 2720 blocks
#define PROJ_LD 388          // padded stride for proj LDS
#define NTUP    (QT * NHEADS * NLEV * NPTS)   // 2048 tuples per block

typedef short  bf16x8 __attribute__((ext_vector_type(8)));
typedef float  f32x4  __attribute__((ext_vector_type(4)));

static __device__ __host__ inline unsigned short f2bf(float x) {
    unsigned int u = __builtin_bit_cast(unsigned int, x);
    unsigned int r = (u + 0x7fff + ((u >> 16) & 1)) >> 16;   // RNE
    return (unsigned short)r;
}
static __device__ inline unsigned int pack2h(float a, float b) {
    __half2 h = __floats2half2_rn(a, b);
    return __builtin_bit_cast(unsigned int, h);
}
static __device__ inline float2 unpack2h(unsigned int u) {
    return __half22float2(__builtin_bit_cast(__half2, u));
}

// ---- pack W into bf16 B-fragment-major layout in ws ----
__global__ __launch_bounds__(256) void pack_w(
    const float* __restrict__ Woff, const float* __restrict__ Wattn,
    const float* __restrict__ Wout, unsigned short* __restrict__ ws)
{
    const int id = blockIdx.x * 256 + threadIdx.x;   // 0 .. 20479
    bf16x8 pk;
    if (id < 12288) {
        const int lane = id & 63, s = (id >> 6) & 7, tn = id >> 9;
        const int col = tn * 16 + (lane & 15);
        const int k0  = s * 32 + (lane >> 4) * 8;
        #pragma unroll
        for (int i = 0; i < 8; ++i) {
            const int k = k0 + i;
            const float w = (col < 256) ? Woff[(size_t)k * 256 + col]
                                        : Wattn[(size_t)k * 128 + (col - 256)];
            pk[i] = (short)f2bf(w);
        }
        *(bf16x8*)(ws + (size_t)id * 8) = pk;
    } else {
        const int id2 = id - 12288;
        const int lane = id2 & 63, s = (id2 >> 6) & 7, tn = id2 >> 9;
        const int col = tn * 16 + (lane & 15);
        const int k0  = s * 32 + (lane >> 4) * 8;
        #pragma unroll
        for (int i = 0; i < 8; ++i)
            pk[i] = (short)f2bf(Wout[(size_t)(k0 + i) * 256 + col]);
        *(bf16x8*)(ws + (size_t)(12288 + id2) * 8) = pk;
    }
}

// A-frag reader: xqb is [16 rows][512 B] bf16, column-XOR-swizzled:
// element (row,k) lives at byte row*512 + ((k*2) ^ ((row&7)<<4))
static __device__ inline void load_afrags(const unsigned char* xqb, int lane, bf16x8* af) {
    const int row = lane & 15;
    const int kg8 = (lane >> 4) * 8;
    const int sw  = (row & 7) << 4;
    const int base = row * 512;
    #pragma unroll
    for (int s = 0; s < 8; ++s) {
        const int byte = base + (((s * 32 + kg8) * 2) ^ sw);
        af[s] = *(const bf16x8*)(xqb + byte);
    }
}

__global__ __launch_bounds__(256, 4) void msda_fused(
    const float* __restrict__ query,     // [B][LQ][256]
    const float* __restrict__ refp,      // [B][LQ][2]
    const float* __restrict__ feat,      // [B][LQ][256]
    const float* __restrict__ boff,      // [256]
    const float* __restrict__ battn,     // [128]
    const float* __restrict__ bout,      // [256]
    const unsigned short* __restrict__ wsB,   // packed [Woff|Wattn] frags
    const unsigned short* __restrict__ wsO,   // packed Wout frags
    float* __restrict__ out)             // [B][LQ][256]
{
    __shared__ __align__(16) unsigned char xqb[QT * 512];       // bf16 A-tile (query, then mid)
    __shared__ __align__(16) float proj[QT * PROJ_LD];          // [off|attn], then tuple arrays
    __shared__ float rp[QT][2];

    const int t    = threadIdx.x;
    const int lane = t & 63;
    const int wid  = t >> 6;
    const int q0   = blockIdx.x * QT;
    const int b    = q0 / LQ;

    #define PROJ(q, c) proj[(q) * PROJ_LD + (c)]
    // tuple overlay (proj is dead once tuples are built): 3 arrays of 2048 ints = 24 KB
    int*          toff = (int*)proj;
    unsigned int* tw01 = (unsigned int*)proj + NTUP;
    unsigned int* tw23 = (unsigned int*)proj + 2 * NTUP;

    // ---- Phase A: stage 16 query rows as swizzled bf16 + ref points ----
    {
        const float4* src = (const float4*)(query + (size_t)q0 * CDIM);
        #pragma unroll
        for (int i = 0; i < 4; ++i) {
            const int idx = t + i * 256;          // 0..1023 float4s
            const int row = idx >> 6;             // 64 float4 per row
            const int k4  = (idx & 63) * 4;       // element k base
            const float4 v = src[idx];
            uint2 w;
            w.x = (unsigned int)f2bf(v.x) | ((unsigned int)f2bf(v.y) << 16);
            w.y = (unsigned int)f2bf(v.z) | ((unsigned int)f2bf(v.w) << 16);
            const int byte = row * 512 + (((k4 * 2)) ^ ((row & 7) << 4));
            *(uint2*)(xqb + byte) = w;
        }
        if (t < QT * 2) ((float*)rp)[t] = refp[(size_t)q0 * 2 + t];
    }
    __syncthreads();

    // ---- Phase B: proj[q][c] = query . [Woff|Wattn] + bias via MFMA ----
    {
        bf16x8 af[8];
        load_afrags(xqb, lane, af);
        const int colb = lane & 15;
        const int r0   = (lane >> 4) * 4;
        #pragma unroll
        for (int j = 0; j < 6; ++j) {
            const int tn  = wid * 6 + j;          // 0..23
            const int col = tn * 16 + colb;
            const float bv = (col < 256) ? boff[col] : battn[col - 256];
            f32x4 acc = {bv, bv, bv, bv};
            const bf16x8* bp = (const bf16x8*)wsB + (size_t)tn * 8 * 64 + lane;
            #pragma unroll
            for (int s = 0; s < 8; ++s)
                acc = __builtin_amdgcn_mfma_f32_16x16x32_bf16(af[s], bp[(size_t)s * 64], acc, 0, 0, 0);
            #pragma unroll
            for (int r = 0; r < 4; ++r) PROJ(r0 + r, col) = acc[r];
        }
    }
    __syncthreads();

    // ---- Phase C: softmax over the 16 attn logits per (q, h) ----
    if (t < QT * NHEADS) {
        const int q = t >> 3, h = t & 7;
        float* a = &PROJ(q, CDIM + h * 16);
        float m = a[0];
        #pragma unroll
        for (int j = 1; j < 16; ++j) m = fmaxf(m, a[j]);
        float e[16], s = 0.f;
        #pragma unroll
        for (int j = 0; j < 16; ++j) { e[j] = __expf(a[j] - m); s += e[j]; }
        const float inv = 1.f / s;
        #pragma unroll
        for (int j = 0; j < 16; ++j) a[j] = e[j] * inv;
    }
    __syncthreads();

    // ---- Phase D0: build sampling tuples (reg-stage, then overlay onto proj) ----
    // tuple id = ((q*8 + h) * 16) + (l*4 + p); payload {off00_raw, w00|w01, w10|w11}
    int   r_off[8];
    unsigned int r_w01[8], r_w23[8];
    {
        const int LW[4] = {128, 64, 32, 16};
        const int LS[4] = {0, 16384, 20480, 21504};
        #pragma unroll
        for (int k = 0; k < 8; ++k) {
            const int tupid = t * 8 + k;
            const int q  = tupid >> 7;
            const int h  = (tupid >> 4) & 7;
            const int lp = tupid & 15;
            const int l  = lp >> 2, p = lp & 3;
            const int Wl = LW[l], Hl = LW[l];
            const float ox = PROJ(q, ((h * NLEV + l) * NPTS + p) * 2 + 0);
            const float oy = PROJ(q, ((h * NLEV + l) * NPTS + p) * 2 + 1);
            const float aw = PROJ(q, CDIM + h * 16 + lp);
            const float x = rp[q][0] * (float)Wl + ox - 0.5f;
            const float y = rp[q][1] * (float)Hl + oy - 0.5f;
            const float x0f = floorf(x), y0f = floorf(y);
            const float fx = x - x0f, fy = y - y0f;
            const int ix = (int)x0f, iy = (int)y0f;
            const bool vx0 = (ix >= 0) & (ix < Wl), vx1 = (ix >= -1) & (ix < Wl - 1);
            const bool vy0 = (iy >= 0) & (iy < Hl), vy1 = (iy >= -1) & (iy < Hl - 1);
            const float w00 = (vx0 & vy0) ? (1.f - fx) * (1.f - fy) * aw : 0.f;
            const float w01 = (vx1 & vy0) ? fx * (1.f - fy) * aw : 0.f;
            const float w10 = (vx0 & vy1) ? (1.f - fx) * fy * aw : 0.f;
            const float w11 = (vx1 & vy1) ? fx * fy * aw : 0.f;
            r_off[k] = LS[l] + iy * Wl + ix;
            r_w01[k] = pack2h(w00, w01);
            r_w23[k] = pack2h(w10, w11);
        }
    }
    __syncthreads();
    #pragma unroll
    for (int k = 0; k < 8; ++k) {
        const int tupid = t * 8 + k;
        toff[tupid] = r_off[k];
        tw01[tupid] = r_w01[k];
        tw23[tupid] = r_w23[k];
    }
    __syncthreads();

    // ---- Phase D1: gather; thread t -> (qg = t>>6, h = (t>>3)&7, d4 = t&7) ----
    {
        const int qg = t >> 6, h = (t >> 3) & 7, d4 = t & 7;
        const float* featb = feat + (size_t)b * LQ * CDIM + h * HDIM + d4 * 4;
        #pragma unroll
        for (int j = 0; j < 4; ++j) {
            const int q = qg * 4 + j;
            const int tbase = (q * 8 + h) * 16;
            f32x4 acc = {0.f, 0.f, 0.f, 0.f};
            #pragma unroll
            for (int lp = 0; lp < 16; ++lp) {
                const int Wl = (lp < 4) ? 128 : (lp < 8) ? 64 : (lp < 12) ? 32 : 16;
                const int off00 = toff[tbase + lp];
                const float2 wlo = unpack2h(tw01[tbase + lp]);
                const float2 whi = unpack2h(tw23[tbase + lp]);
                const int o0 = (wlo.x != 0.f) ? off00          : 0;
                const int o1 = (wlo.y != 0.f) ? off00 + 1      : 0;
                const int o2 = (whi.x != 0.f) ? off00 + Wl     : 0;
                const int o3 = (whi.y != 0.f) ? off00 + Wl + 1 : 0;
                const f32x4 v0 = *(const f32x4*)(featb + (long)o0 * CDIM);
                const f32x4 v1 = *(const f32x4*)(featb + (long)o1 * CDIM);
                const f32x4 v2 = *(const f32x4*)(featb + (long)o2 * CDIM);
                const f32x4 v3 = *(const f32x4*)(featb + (long)o3 * CDIM);
                acc += wlo.x * v0;
                acc += wlo.y * v1;
                acc += whi.x * v2;
                acc += whi.y * v3;
            }
            // write mid[q][h*32+d4*4 .. +3] as swizzled bf16 (8B store)
            uint2 wv;
            wv.x = (unsigned int)f2bf(acc[0]) | ((unsigned int)f2bf(acc[1]) << 16);
            wv.y = (unsigned int)f2bf(acc[2]) | ((unsigned int)f2bf(acc[3]) << 16);
            const int byte = q * 512 + (((h * HDIM + d4 * 4) * 2) ^ ((q & 7) << 4));
            *(uint2*)(xqb + byte) = wv;
        }
    }
    __syncthreads();

    // ---- Phase E: out[q][n] = mid . Wout + bout via MFMA, direct global store ----
    {
        bf16x8 af[8];
        load_afrags(xqb, lane, af);
        const int colb = lane & 15;
        const int r0   = (lane >> 4) * 4;
        #pragma unroll
        for (int j = 0; j < 4; ++j) {
            const int tn  = wid * 4 + j;          // 0..15
            const int col = tn * 16 + colb;
            const float bv = bout[col];
            f32x4 acc = {bv, bv, bv, bv};
            const bf16x8* bp = (const bf16x8*)wsO + (size_t)tn * 8 * 64 + lane;
            #pragma unroll
            for (int s = 0; s < 8; ++s)
                acc = __builtin_amdgcn_mfma_f32_16x16x32_bf16(af[s], bp[(size_t)s * 64], acc, 0, 0, 0);
            #pragma unroll
            for (int r = 0; r < 4; ++r)
                out[(size_t)(q0 + r0 + r) * CDIM + col] = acc[r];
        }
    }
    #undef PROJ
}

extern "C" void kernel_launch(void* const* d_in, const int* in_sizes, int n_in,
                              void* d_out, int out_size, void* d_ws, size_t ws_size,
                              hipStream_t stream) {
    const float* query = (const float*)d_in[0];
    const float* refp  = (const float*)d_in[1];
    const float* feat  = (const float*)d_in[2];
    const float* Woff  = (const float*)d_in[5];
    const float* boff  = (const float*)d_in[6];
    const float* Wattn = (const float*)d_in[7];
    const float* battn = (const float*)d_in[8];
    const float* Wout  = (const float*)d_in[9];
    const float* bout  = (const float*)d_in[10];
    float* out = (float*)d_out;

    unsigned short* ws = (unsigned short*)d_ws;
    const unsigned short* wsB = ws;                       // 12288 frags * 16B
    const unsigned short* wsO = ws + (size_t)12288 * 8;   // 8192 frags * 16B

    hipLaunchKernelGGL(pack_w, dim3(80), dim3(256), 0, stream, Woff, Wattn, Wout, ws);

    const int nrows = BATCH * LQ;            // 43520
    hipLaunchKernelGGL(msda_fused, dim3(nrows / QT), dim3(256), 0, stream,
                       query, refp, feat, boff, battn, bout, wsB, wsO, out);
}

// Round 4
// 144.370 us; speedup vs baseline: 8.3366x; 1.1018x over previous
//
#include <hip/hip_runtime.h>
#include <hip/hip_fp16.h>
#include <math.h>

// Problem constants (fixed by setup_inputs)
#define BATCH   2
#define LQ      21760
#define CDIM    256
#define NHEADS  8
#define NLEV    4
#define NPTS    4
#define HDIM    32
#define QT      16           // queries per block; 43520/16 = 2720 blocks
#define PROJ_LDH 392         // f16 proj stride (384 cols + 8 pad)

typedef short  bf16x8 __attribute__((ext_vector_type(8)));
typedef float  f32x4  __attribute__((ext_vector_type(4)));
typedef unsigned int u32x4 __attribute__((ext_vector_type(4)));
typedef unsigned short u16x8 __attribute__((ext_vector_type(8)));

static __device__ __host__ inline unsigned short f2bf(float x) {
    unsigned int u = __builtin_bit_cast(unsigned int, x);
    unsigned int r = (u + 0x7fff + ((u >> 16) & 1)) >> 16;   // RNE
    return (unsigned short)r;
}
static __device__ inline unsigned int pack2h(float a, float b) {
    __half2 h = __floats2half2_rn(a, b);
    return __builtin_bit_cast(unsigned int, h);
}
static __device__ inline float2 unpack2h(unsigned int u) {
    return __half22float2(__builtin_bit_cast(__half2, u));
}
static __device__ inline float bfhi(unsigned int u) {   // high bf16 -> f32
    return __builtin_bit_cast(float, u & 0xffff0000u);
}
static __device__ inline float bflo(unsigned int u) {   // low bf16 -> f32
    return __builtin_bit_cast(float, u << 16);
}

// ---- pack feat f32 -> bf16 into ws ----
__global__ __launch_bounds__(256) void pack_feat(
    const float* __restrict__ f, unsigned short* __restrict__ o)
{
    const size_t i8 = ((size_t)blockIdx.x * 256 + threadIdx.x) * 8;
    const float4 v0 = *(const float4*)(f + i8);
    const float4 v1 = *(const float4*)(f + i8 + 4);
    u16x8 pk;
    pk[0] = f2bf(v0.x); pk[1] = f2bf(v0.y); pk[2] = f2bf(v0.z); pk[3] = f2bf(v0.w);
    pk[4] = f2bf(v1.x); pk[5] = f2bf(v1.y); pk[6] = f2bf(v1.z); pk[7] = f2bf(v1.w);
    *(u16x8*)(o + i8) = pk;
}

// ---- pack W into bf16 B-fragment-major layout ----
__global__ __launch_bounds__(256) void pack_w(
    const float* __restrict__ Woff, const float* __restrict__ Wattn,
    const float* __restrict__ Wout, unsigned short* __restrict__ wsB,
    unsigned short* __restrict__ wsO)
{
    const int id = blockIdx.x * 256 + threadIdx.x;   // 0 .. 20479
    bf16x8 pk;
    if (id < 12288) {
        const int lane = id & 63, s = (id >> 6) & 7, tn = id >> 9;
        const int col = tn * 16 + (lane & 15);
        const int k0  = s * 32 + (lane >> 4) * 8;
        #pragma unroll
        for (int i = 0; i < 8; ++i) {
            const int k = k0 + i;
            const float w = (col < 256) ? Woff[(size_t)k * 256 + col]
                                        : Wattn[(size_t)k * 128 + (col - 256)];
            pk[i] = (short)f2bf(w);
        }
        *(bf16x8*)(wsB + (size_t)id * 8) = pk;
    } else {
        const int id2 = id - 12288;
        const int lane = id2 & 63, s = (id2 >> 6) & 7, tn = id2 >> 9;
        const int col = tn * 16 + (lane & 15);
        const int k0  = s * 32 + (lane >> 4) * 8;
        #pragma unroll
        for (int i = 0; i < 8; ++i)
            pk[i] = (short)f2bf(Wout[(size_t)(k0 + i) * 256 + col]);
        *(bf16x8*)(wsO + (size_t)id2 * 8) = pk;
    }
}

// A-frag reader: xqb is [16 rows][512 B] bf16, column-XOR-swizzled:
// element (row,k) lives at byte row*512 + ((k*2) ^ ((row&7)<<4))
static __device__ inline void load_afrags(const unsigned char* xqb, int lane, bf16x8* af) {
    const int row = lane & 15;
    const int kg8 = (lane >> 4) * 8;
    const int sw  = (row & 7) << 4;
    const int base = row * 512;
    #pragma unroll
    for (int s = 0; s < 8; ++s) {
        const int byte = base + (((s * 32 + kg8) * 2) ^ sw);
        af[s] = *(const bf16x8*)(xqb + byte);
    }
}

template<bool BF16F>
__global__ __launch_bounds__(256, 5) void msda_fused(
    const float* __restrict__ query,     // [B][LQ][256]
    const float* __restrict__ refp,      // [B][LQ][2]
    const float* __restrict__ feat,      // [B][LQ][256] f32
    const unsigned short* __restrict__ featbf,   // [B][LQ][256] bf16 (if BF16F)
    const float* __restrict__ boff,      // [256]
    const float* __restrict__ battn,     // [128]
    const float* __restrict__ bout,      // [256]
    const unsigned short* __restrict__ wsB,   // packed [Woff|Wattn] frags
    const unsigned short* __restrict__ wsO,   // packed Wout frags
    float* __restrict__ out)             // [B][LQ][256]
{
    __shared__ __align__(16) unsigned char xqb[QT * 512];   // bf16 A-tile (query, then mid)
    __shared__ __align__(16) __half projh[QT * PROJ_LDH];   // f16 [off(256)|attn(128)] per q

    const int t    = threadIdx.x;
    const int lane = t & 63;
    const int wid  = t >> 6;
    const int q0   = blockIdx.x * QT;
    const int b    = q0 / LQ;

    // ---- Phase A: stage 16 query rows as swizzled bf16 ----
    {
        const float4* src = (const float4*)(query + (size_t)q0 * CDIM);
        #pragma unroll
        for (int i = 0; i < 4; ++i) {
            const int idx = t + i * 256;          // 0..1023 float4s
            const int row = idx >> 6;             // 64 float4 per row
            const int k4  = (idx & 63) * 4;       // element k base
            const float4 v = src[idx];
            uint2 w;
            w.x = (unsigned int)f2bf(v.x) | ((unsigned int)f2bf(v.y) << 16);
            w.y = (unsigned int)f2bf(v.z) | ((unsigned int)f2bf(v.w) << 16);
            const int byte = row * 512 + ((k4 * 2) ^ ((row & 7) << 4));
            *(uint2*)(xqb + byte) = w;
        }
    }
    __syncthreads();

    // ---- Phase B: projh[q][c] = query . [Woff|Wattn] + bias via MFMA ----
    {
        bf16x8 af[8];
        load_afrags(xqb, lane, af);
        const int colb = lane & 15;
        const int r0   = (lane >> 4) * 4;
        #pragma unroll
        for (int j = 0; j < 6; ++j) {
            const int tn  = wid * 6 + j;          // 0..23
            const int col = tn * 16 + colb;
            const float bv = (col < 256) ? boff[col] : battn[col - 256];
            f32x4 acc = {bv, bv, bv, bv};
            const bf16x8* bp = (const bf16x8*)wsB + (size_t)tn * 8 * 64 + lane;
            #pragma unroll
            for (int s = 0; s < 8; ++s)
                acc = __builtin_amdgcn_mfma_f32_16x16x32_bf16(af[s], bp[(size_t)s * 64], acc, 0, 0, 0);
            #pragma unroll
            for (int r = 0; r < 4; ++r)
                projh[(r0 + r) * PROJ_LDH + col] = __float2half(acc[r]);
        }
    }
    __syncthreads();

    // ---- Phase C: softmax over the 16 attn logits per (q, h) ----
    if (t < QT * NHEADS) {
        const int q = t >> 3, h = t & 7;
        __half* a = projh + q * PROJ_LDH + 256 + h * 16;
        float v[16];
        #pragma unroll
        for (int j = 0; j < 16; ++j) v[j] = __half2float(a[j]);
        float m = v[0];
        #pragma unroll
        for (int j = 1; j < 16; ++j) m = fmaxf(m, v[j]);
        float s = 0.f;
        #pragma unroll
        for (int j = 0; j < 16; ++j) { v[j] = __expf(v[j] - m); s += v[j]; }
        const float inv = 1.f / s;
        #pragma unroll
        for (int j = 0; j < 16; ++j) a[j] = __float2half(v[j] * inv);
    }
    __syncthreads();

    // ---- Phase D0: each thread builds 8 tuples for its (q_own, h_own, half) ----
    // tuple (q,h,lp) lives in lane (q&3)*16 + h*2 + (lp>>3), register k = lp&7
    int r_off[8]; int r_w01[8]; int r_w23[8];
    {
        const int q_own = t >> 4;
        const int h_own = (t >> 1) & 7;
        const int lpb   = (t & 1) * 8;
        const float rx = refp[(size_t)(q0 + q_own) * 2 + 0];
        const float ry = refp[(size_t)(q0 + q_own) * 2 + 1];
        const int LW[4] = {128, 64, 32, 16};
        const int LS[4] = {0, 16384, 20480, 21504};
        #pragma unroll
        for (int k = 0; k < 8; ++k) {
            const int lp = lpb + k;
            const int l = lp >> 2, p = lp & 3;
            const int Wl = LW[l], Hl = LW[l];
            const unsigned int oxy = *(const unsigned int*)(projh + q_own * PROJ_LDH
                                        + ((h_own * NLEV + l) * NPTS + p) * 2);
            const float2 oo = unpack2h(oxy);
            const float aw = __half2float(projh[q_own * PROJ_LDH + 256 + h_own * 16 + lp]);
            const float x = rx * (float)Wl + oo.x - 0.5f;
            const float y = ry * (float)Hl + oo.y - 0.5f;
            const float x0f = floorf(x), y0f = floorf(y);
            const float fx = x - x0f, fy = y - y0f;
            const int ix = (int)x0f, iy = (int)y0f;
            const bool vx0 = (ix >= 0) & (ix < Wl), vx1 = (ix >= -1) & (ix < Wl - 1);
            const bool vy0 = (iy >= 0) & (iy < Hl), vy1 = (iy >= -1) & (iy < Hl - 1);
            const float w00 = (vx0 & vy0) ? (1.f - fx) * (1.f - fy) * aw : 0.f;
            const float w01 = (vx1 & vy0) ? fx * (1.f - fy) * aw : 0.f;
            const float w10 = (vx0 & vy1) ? (1.f - fx) * fy * aw : 0.f;
            const float w11 = (vx1 & vy1) ? fx * fy * aw : 0.f;
            r_off[k] = LS[l] + iy * Wl + ix;
            r_w01[k] = (int)pack2h(w00, w01);
            r_w23[k] = (int)pack2h(w10, w11);
        }
    }
    // no barrier needed: producers and consumers are in the same wave

    // ---- Phase D1: gather; thread -> (d8 = t&3, h = (t>>2)&7, qpar = (t>>5)&1) ----
    {
        const int d8   = t & 3;
        const int h    = (t >> 2) & 7;
        const int qpar = (t >> 5) & 1;
        const int qg   = t >> 6;
        const int chb  = h * HDIM + d8 * 8;       // channel base
        #pragma unroll
        for (int j = 0; j < 2; ++j) {
            const int q = qg * 4 + j * 2 + qpar;
            const int srcb = (q & 3) * 16 + h * 2;
            float a0 = 0.f, a1 = 0.f, a2 = 0.f, a3 = 0.f;
            float a4 = 0.f, a5 = 0.f, a6 = 0.f, a7 = 0.f;
            #pragma unroll
            for (int lp = 0; lp < 16; ++lp) {
                const int k = lp & 7;
                const int src = srcb + (lp >> 3);
                const int Wl = (lp < 4) ? 128 : (lp < 8) ? 64 : (lp < 12) ? 32 : 16;
                const int off00 = __shfl(r_off[k], src);
                const float2 wlo = unpack2h((unsigned int)__shfl(r_w01[k], src));
                const float2 whi = unpack2h((unsigned int)__shfl(r_w23[k], src));
                const int o0 = (wlo.x != 0.f) ? off00          : 0;
                const int o1 = (wlo.y != 0.f) ? off00 + 1      : 0;
                const int o2 = (whi.x != 0.f) ? off00 + Wl     : 0;
                const int o3 = (whi.y != 0.f) ? off00 + Wl + 1 : 0;
                if (BF16F) {
                    const unsigned short* fb = featbf + (size_t)b * LQ * CDIM + chb;
                    const u32x4 v0 = *(const u32x4*)(fb + (long)o0 * CDIM);
                    const u32x4 v1 = *(const u32x4*)(fb + (long)o1 * CDIM);
                    const u32x4 v2 = *(const u32x4*)(fb + (long)o2 * CDIM);
                    const u32x4 v3 = *(const u32x4*)(fb + (long)o3 * CDIM);
                    a0 = fmaf(wlo.x, bflo(v0[0]), a0); a1 = fmaf(wlo.x, bfhi(v0[0]), a1);
                    a2 = fmaf(wlo.x, bflo(v0[1]), a2); a3 = fmaf(wlo.x, bfhi(v0[1]), a3);
                    a4 = fmaf(wlo.x, bflo(v0[2]), a4); a5 = fmaf(wlo.x, bfhi(v0[2]), a5);
                    a6 = fmaf(wlo.x, bflo(v0[3]), a6); a7 = fmaf(wlo.x, bfhi(v0[3]), a7);
                    a0 = fmaf(wlo.y, bflo(v1[0]), a0); a1 = fmaf(wlo.y, bfhi(v1[0]), a1);
                    a2 = fmaf(wlo.y, bflo(v1[1]), a2); a3 = fmaf(wlo.y, bfhi(v1[1]), a3);
                    a4 = fmaf(wlo.y, bflo(v1[2]), a4); a5 = fmaf(wlo.y, bfhi(v1[2]), a5);
                    a6 = fmaf(wlo.y, bflo(v1[3]), a6); a7 = fmaf(wlo.y, bfhi(v1[3]), a7);
                    a0 = fmaf(whi.x, bflo(v2[0]), a0); a1 = fmaf(whi.x, bfhi(v2[0]), a1);
                    a2 = fmaf(whi.x, bflo(v2[1]), a2); a3 = fmaf(whi.x, bfhi(v2[1]), a3);
                    a4 = fmaf(whi.x, bflo(v2[2]), a4); a5 = fmaf(whi.x, bfhi(v2[2]), a5);
                    a6 = fmaf(whi.x, bflo(v2[3]), a6); a7 = fmaf(whi.x, bfhi(v2[3]), a7);
                    a0 = fmaf(whi.y, bflo(v3[0]), a0); a1 = fmaf(whi.y, bfhi(v3[0]), a1);
                    a2 = fmaf(whi.y, bflo(v3[1]), a2); a3 = fmaf(whi.y, bfhi(v3[1]), a3);
                    a4 = fmaf(whi.y, bflo(v3[2]), a4); a5 = fmaf(whi.y, bfhi(v3[2]), a5);
                    a6 = fmaf(whi.y, bflo(v3[3]), a6); a7 = fmaf(whi.y, bfhi(v3[3]), a7);
                } else {
                    const float* fb = feat + (size_t)b * LQ * CDIM + chb;
                    const f32x4 v0a = *(const f32x4*)(fb + (long)o0 * CDIM);
                    const f32x4 v0b = *(const f32x4*)(fb + (long)o0 * CDIM + 4);
                    const f32x4 v1a = *(const f32x4*)(fb + (long)o1 * CDIM);
                    const f32x4 v1b = *(const f32x4*)(fb + (long)o1 * CDIM + 4);
                    const f32x4 v2a = *(const f32x4*)(fb + (long)o2 * CDIM);
                    const f32x4 v2b = *(const f32x4*)(fb + (long)o2 * CDIM + 4);
                    const f32x4 v3a = *(const f32x4*)(fb + (long)o3 * CDIM);
                    const f32x4 v3b = *(const f32x4*)(fb + (long)o3 * CDIM + 4);
                    a0 = fmaf(wlo.x, v0a[0], a0); a1 = fmaf(wlo.x, v0a[1], a1);
                    a2 = fmaf(wlo.x, v0a[2], a2); a3 = fmaf(wlo.x, v0a[3], a3);
                    a4 = fmaf(wlo.x, v0b[0], a4); a5 = fmaf(wlo.x, v0b[1], a5);
                    a6 = fmaf(wlo.x, v0b[2], a6); a7 = fmaf(wlo.x, v0b[3], a7);
                    a0 = fmaf(wlo.y, v1a[0], a0); a1 = fmaf(wlo.y, v1a[1], a1);
                    a2 = fmaf(wlo.y, v1a[2], a2); a3 = fmaf(wlo.y, v1a[3], a3);
                    a4 = fmaf(wlo.y, v1b[0], a4); a5 = fmaf(wlo.y, v1b[1], a5);
                    a6 = fmaf(wlo.y, v1b[2], a6); a7 = fmaf(wlo.y, v1b[3], a7);
                    a0 = fmaf(whi.x, v2a[0], a0); a1 = fmaf(whi.x, v2a[1], a1);
                    a2 = fmaf(whi.x, v2a[2], a2); a3 = fmaf(whi.x, v2a[3], a3);
                    a4 = fmaf(whi.x, v2b[0], a4); a5 = fmaf(whi.x, v2b[1], a5);
                    a6 = fmaf(whi.x, v2b[2], a6); a7 = fmaf(whi.x, v2b[3], a7);
                    a0 = fmaf(whi.y, v3a[0], a0); a1 = fmaf(whi.y, v3a[1], a1);
                    a2 = fmaf(whi.y, v3a[2], a2); a3 = fmaf(whi.y, v3a[3], a3);
                    a4 = fmaf(whi.y, v3b[0], a4); a5 = fmaf(whi.y, v3b[1], a5);
                    a6 = fmaf(whi.y, v3b[2], a6); a7 = fmaf(whi.y, v3b[3], a7);
                }
            }
            // write mid[q][chb .. chb+7] as swizzled bf16 (16B store)
            u32x4 wv;
            wv[0] = (unsigned int)f2bf(a0) | ((unsigned int)f2bf(a1) << 16);
            wv[1] = (unsigned int)f2bf(a2) | ((unsigned int)f2bf(a3) << 16);
            wv[2] = (unsigned int)f2bf(a4) | ((unsigned int)f2bf(a5) << 16);
            wv[3] = (unsigned int)f2bf(a6) | ((unsigned int)f2bf(a7) << 16);
            const int byte = q * 512 + (((chb) * 2) ^ ((q & 7) << 4));
            *(u32x4*)(xqb + byte) = wv;
        }
    }
    __syncthreads();

    // ---- Phase E: out[q][n] = mid . Wout + bout via MFMA, direct global store ----
    {
        bf16x8 af[8];
        load_afrags(xqb, lane, af);
        const int colb = lane & 15;
        const int r0   = (lane >> 4) * 4;
        #pragma unroll
        for (int j = 0; j < 4; ++j) {
            const int tn  = wid * 4 + j;          // 0..15
            const int col = tn * 16 + colb;
            const float bv = bout[col];
            f32x4 acc = {bv, bv, bv, bv};
            const bf16x8* bp = (const bf16x8*)wsO + (size_t)tn * 8 * 64 + lane;
            #pragma unroll
            for (int s = 0; s < 8; ++s)
                acc = __builtin_amdgcn_mfma_f32_16x16x32_bf16(af[s], bp[(size_t)s * 64], acc, 0, 0, 0);
            #pragma unroll
            for (int r = 0; r < 4; ++r)
                out[(size_t)(q0 + r0 + r) * CDIM + col] = acc[r];
        }
    }
}

extern "C" void kernel_launch(void* const* d_in, const int* in_sizes, int n_in,
                              void* d_out, int out_size, void* d_ws, size_t ws_size,
                              hipStream_t stream) {
    const float* query = (const float*)d_in[0];
    const float* refp  = (const float*)d_in[1];
    const float* feat  = (const float*)d_in[2];
    const float* Woff  = (const float*)d_in[5];
    const float* boff  = (const float*)d_in[6];
    const float* Wattn = (const float*)d_in[7];
    const float* battn = (const float*)d_in[8];
    const float* Wout  = (const float*)d_in[9];
    const float* bout  = (const float*)d_in[10];
    float* out = (float*)d_out;

    unsigned short* ws = (unsigned short*)d_ws;
    const size_t feat_us = (size_t)BATCH * LQ * CDIM;        // 11,141,120 ushorts
    const size_t need    = (feat_us + 98304 + 65536) * 2;    // bytes
    const bool usebf = ws_size >= need;

    const int nrows = BATCH * LQ;            // 43520

    if (usebf) {
        unsigned short* featbf = ws;
        unsigned short* wsB = ws + feat_us;
        unsigned short* wsO = wsB + 98304;
        pack_feat<<<dim3((unsigned)(feat_us / 8 / 256)), dim3(256), 0, stream>>>(feat, featbf);
        pack_w<<<dim3(80), dim3(256), 0, stream>>>(Woff, Wattn, Wout, wsB, wsO);
        msda_fused<true><<<dim3(nrows / QT), dim3(256), 0, stream>>>(
            query, refp, feat, featbf, boff, battn, bout, wsB, wsO, out);
    } else {
        unsigned short* wsB = ws;
        unsigned short* wsO = ws + 98304;
        pack_w<<<dim3(80), dim3(256), 0, stream>>>(Woff, Wattn, Wout, wsB, wsO);
        msda_fused<false><<<dim3(nrows / QT), dim3(256), 0, stream>>>(
            query, refp, feat, (const unsigned short*)nullptr, boff, battn, bout, wsB, wsO, out);
    }
}